// Round 3
// baseline (6494.012 us; speedup 1.0000x reference)
//
#include <hip/hip_runtime.h>
#include <math.h>

constexpr int B = 2;
constexpr int N = 10000;
constexpr int K = 10;
constexpr int NK = N * K;
constexpr float NEG = 0.2f;
constexpr float BN_EPS = 1e-5f;
constexpr int SB = 64;   // stats partial blocks per channel
constexpr int JS = 8;    // knn j-range splits

#define DEV __device__ __forceinline__

// ---------------- squared norms ----------------
__global__ void __launch_bounds__(256, 4)
xx_kernel(const float* __restrict__ x, long bstride, int C,
          float* __restrict__ xx) {
  int n = blockIdx.x * 256 + threadIdx.x;
  int b = blockIdx.y;
  if (n >= N) return;
  const float* xb = x + (long)b * bstride;
  float s = 0.f;
  for (int c = 0; c < C; ++c) { float v = xb[(long)c * N + n]; s += v * v; }
  xx[b * N + n] = s;
}

// ---------------- top-K insertion, lexicographic (d, j) ----------------
// Order-independent and matches lax.top_k stable tie-break (lower index first).
DEV bool lex_lt(float d1, int j1, float d2, int j2) {
  return d1 < d2 || (d1 == d2 && j1 < j2);
}
DEV void topk_insert(float (&dbest)[K], int (&ibest)[K], float d, int j) {
  float dn = d; int jn = j;
#pragma unroll
  for (int s = 0; s < K; ++s) {
    if (lex_lt(dn, jn, dbest[s], ibest[s])) {
      float td = dbest[s]; int tj = ibest[s];
      dbest[s] = dn; ibest[s] = jn;
      dn = td; jn = tj;
    }
  }
}

// ---------------- knn partial for C=3 (cheap, per-thread query) ----------------
template<int C, int TJ, int PAD>
__global__ void __launch_bounds__(256, 4)
knn_partial_kernel(const float* __restrict__ x, long bstride,
                   const float* __restrict__ xx,
                   float* __restrict__ pd, int* __restrict__ pi) {
  __shared__ __align__(16) float sx[TJ][PAD];
  __shared__ float sxx[TJ];
  int b = blockIdx.z;
  int js = blockIdx.y;
  int q = blockIdx.x * 256 + threadIdx.x;
  bool valid = q < N;
  const int CH = (N + JS - 1) / JS;
  int jbeg = js * CH;
  int jend = min(N, jbeg + CH);
  const float* xb = x + (long)b * bstride;
  float xi[C];
  float xxi = 0.f;
  if (valid) {
#pragma unroll
    for (int c = 0; c < C; ++c) xi[c] = xb[(long)c * N + q];
    xxi = xx[b * N + q];
  }
  float dbest[K]; int ibest[K];
#pragma unroll
  for (int k = 0; k < K; ++k) { dbest[k] = 3.4e38f; ibest[k] = 0x7fffffff; }

  for (int j0 = jbeg; j0 < jend; j0 += TJ) {
    int cnt = min(TJ, jend - j0);
    __syncthreads();
    for (int e = threadIdx.x; e < C * TJ; e += 256) {
      int tj = e & (TJ - 1);
      int c = e / TJ;
      sx[tj][c] = (tj < cnt) ? xb[(long)c * N + j0 + tj] : 0.f;
    }
    for (int e = threadIdx.x; e < TJ; e += 256)
      sxx[e] = (e < cnt) ? xx[b * N + j0 + e] : 0.f;
    __syncthreads();
    if (!valid) continue;
    for (int tj = 0; tj < cnt; ++tj) {
      float dot = 0.f;
#pragma unroll
      for (int c = 0; c < C; ++c) dot += xi[c] * sx[tj][c];
      float d = xxi - 2.f * dot + sxx[tj];
      int j = j0 + tj;
      if (j != q && lex_lt(d, j, dbest[K - 1], ibest[K - 1]))
        topk_insert(dbest, ibest, d, j);
    }
  }
  if (valid) {
    long base = ((long)(b * N + q) * JS + js) * K;
#pragma unroll
    for (int k = 0; k < K; ++k) { pd[base + k] = dbest[k]; pi[base + k] = ibest[k]; }
  }
}

// ---------------- knn C=64: tiled distance-GEMM + fused top-k ----------------
// Block = 64 queries x (N/JS) j-range. Q-tile LDS once; J-tiles of 128;
// per-thread 4q x 8j register outer product; distances -> LDS (alias J);
// rotated per-q scan (bank-conflict-free) keeps register top-K.
__global__ void __launch_bounds__(256, 2)
knn64_tiled_kernel(const float* __restrict__ x, long bstride,
                   const float* __restrict__ xx,
                   float* __restrict__ pd, int* __restrict__ pi) {
  __shared__ __align__(16) float Qt[64 * 68];    // [c][q], pad 68
  __shared__ __align__(16) float JD[64 * 132];   // [c][j] pad 132; aliased as D[q][j]
  __shared__ float xxq[64];
  __shared__ float xxj[128];
  int b = blockIdx.z, js = blockIdx.y, qt = blockIdx.x;
  int t = threadIdx.x;
  const float* xb = x + (long)b * bstride;
  const float* xxb = xx + b * N;
  int q0 = qt * 64;
  // load Q tile (64 q x 64 c), coalesced along q
#pragma unroll
  for (int r = 0; r < 16; ++r) {
    int e = t + r * 256;
    int q = e & 63, c = e >> 6;
    int qg = q0 + q;
    Qt[c * 68 + q] = (qg < N) ? xb[(long)c * N + qg] : 0.f;
  }
  if (t < 64) xxq[t] = (q0 + t < N) ? xxb[q0 + t] : 0.f;

  const int CH = N / JS;               // 1250
  int jbeg = js * CH, jend = jbeg + CH;
  int tx = t & 15, ty = t >> 4;        // compute-phase coords
  int sq = t & 63, quarter = t >> 6;   // scan-phase coords (quarter == wave id)
  int qg_scan = q0 + sq;

  float dbest[K]; int ibest[K];
#pragma unroll
  for (int k = 0; k < K; ++k) { dbest[k] = 3.4e38f; ibest[k] = 0x7fffffff; }

  for (int jb = jbeg; jb < jend; jb += 128) {
    __syncthreads();  // previous scan done before overwriting JD
    // load J tile (128 j x 64 c)
#pragma unroll
    for (int r = 0; r < 32; ++r) {
      int e = t + r * 256;
      int j = e & 127, c = e >> 7;
      int jg = jb + j;
      JD[c * 132 + j] = (jg < jend) ? xb[(long)c * N + jg] : 0.f;
    }
    if (t < 128) xxj[t] = (jb + t < jend) ? xxb[jb + t] : 3.4e38f;
    __syncthreads();

    float acc[4][8] = {};
#pragma unroll 4
    for (int c = 0; c < 64; ++c) {
      float4 aq = *(const float4*)&Qt[c * 68 + ty * 4];
      float4 b0 = *(const float4*)&JD[c * 132 + tx * 4];
      float4 b1 = *(const float4*)&JD[c * 132 + 64 + tx * 4];
      float av[4] = {aq.x, aq.y, aq.z, aq.w};
      float bv[8] = {b0.x, b0.y, b0.z, b0.w, b1.x, b1.y, b1.z, b1.w};
#pragma unroll
      for (int i = 0; i < 4; ++i)
#pragma unroll
        for (int jj = 0; jj < 8; ++jj) acc[i][jj] += av[i] * bv[jj];
    }
    __syncthreads();  // all reads of JD done
    // distances into JD as D[q][j]
#pragma unroll
    for (int i = 0; i < 4; ++i) {
      int q = ty * 4 + i;
      float xq = xxq[q];
      float4 w0, w1;
      w0.x = xq - 2.f * acc[i][0] + xxj[tx * 4 + 0];
      w0.y = xq - 2.f * acc[i][1] + xxj[tx * 4 + 1];
      w0.z = xq - 2.f * acc[i][2] + xxj[tx * 4 + 2];
      w0.w = xq - 2.f * acc[i][3] + xxj[tx * 4 + 3];
      w1.x = xq - 2.f * acc[i][4] + xxj[64 + tx * 4 + 0];
      w1.y = xq - 2.f * acc[i][5] + xxj[64 + tx * 4 + 1];
      w1.z = xq - 2.f * acc[i][6] + xxj[64 + tx * 4 + 2];
      w1.w = xq - 2.f * acc[i][7] + xxj[64 + tx * 4 + 3];
      *(float4*)&JD[q * 132 + tx * 4] = w0;
      *(float4*)&JD[q * 132 + 64 + tx * 4] = w1;
    }
    __syncthreads();
    // scan: thread owns query sq, j sub-range [quarter*32, quarter*32+32),
    // rotated by sq so LDS banks are conflict-free: bank=(5*sq+jj)%32.
    int jlim = jend - jb;  // valid local j count in this tile
    for (int jj = 0; jj < 32; ++jj) {
      int jl = quarter * 32 + ((jj + sq) & 31);
      float d = JD[sq * 132 + jl];
      int jg = jb + jl;
      if (jl < jlim && jg != qg_scan &&
          lex_lt(d, jg, dbest[K - 1], ibest[K - 1]))
        topk_insert(dbest, ibest, d, jg);
    }
  }
  __syncthreads();
  // in-block merge across the 4 quarters (lexicographic -> order-independent)
  float* mf = Qt;
  int* mi = (int*)JD;
#pragma unroll
  for (int k = 0; k < K; ++k) {
    mf[(sq * 4 + quarter) * K + k] = dbest[k];
    mi[(sq * 4 + quarter) * K + k] = ibest[k];
  }
  __syncthreads();
  if (t < 64 && q0 + t < N) {
    float fb[K]; int ib2[K];
#pragma unroll
    for (int k = 0; k < K; ++k) { fb[k] = 3.4e38f; ib2[k] = 0x7fffffff; }
    for (int s = 0; s < 4; ++s)
#pragma unroll
      for (int k = 0; k < K; ++k) {
        float d = mf[(t * 4 + s) * K + k];
        int j = mi[(t * 4 + s) * K + k];
        if (lex_lt(d, j, fb[K - 1], ib2[K - 1])) topk_insert(fb, ib2, d, j);
      }
    long base = ((long)(b * N + q0 + t) * JS + js) * K;
#pragma unroll
    for (int k = 0; k < K; ++k) { pd[base + k] = fb[k]; pi[base + k] = ib2[k]; }
  }
}

// ---------------- knn merge (JS sorted partial lists -> final top-K) ----------------
__global__ void __launch_bounds__(256, 4)
knn_merge_kernel(const float* __restrict__ pd, const int* __restrict__ pi,
                 int* __restrict__ idx) {
  int t = blockIdx.x * 256 + threadIdx.x;
  if (t >= B * N) return;
  float dbest[K]; int ibest[K];
#pragma unroll
  for (int k = 0; k < K; ++k) { dbest[k] = 3.4e38f; ibest[k] = 0x7fffffff; }
  for (int s = 0; s < JS; ++s) {
    long base = ((long)t * JS + s) * K;
#pragma unroll
    for (int k = 0; k < K; ++k) {
      float d = pd[base + k];
      int j = pi[base + k];
      if (lex_lt(d, j, dbest[K - 1], ibest[K - 1])) topk_insert(dbest, ibest, d, j);
    }
  }
#pragma unroll
  for (int k = 0; k < K; ++k) idx[(long)t * K + k] = ibest[k];
}

// ---------------- generic tiled SGEMM: Y[b][o][m] = sum_c W[o*Wld+c] * X[b][c][m] (+bias[b][o]) ----
__global__ void __launch_bounds__(256, 4)
gemm_kernel(const float* __restrict__ W, int Wld,
            const float* __restrict__ X, long xbstride,
            float* __restrict__ Y, const float* __restrict__ bias,
            int Co, int Cin, int M) {
  __shared__ float Wt[16][64];
  __shared__ float Xt[16][64];
  int b = blockIdx.z;
  int m0 = blockIdx.x * 64;
  int o0 = blockIdx.y * 64;
  const float* Xb = X + (long)b * xbstride;
  int t = threadIdx.x;
  int tx = t & 15, ty = t >> 4;
  float acc[4][4] = {};
  for (int c0 = 0; c0 < Cin; c0 += 16) {
#pragma unroll
    for (int r = 0; r < 4; ++r) {
      int e = t + r * 256;
      int o = e & 63, kc = e >> 6;
      int oo = o0 + o, cc = c0 + kc;
      Wt[kc][o] = (oo < Co && cc < Cin) ? W[(long)oo * Wld + cc] : 0.f;
    }
#pragma unroll
    for (int r = 0; r < 4; ++r) {
      int e = t + r * 256;
      int m = e & 63, kc = e >> 6;
      int mm = m0 + m, cc = c0 + kc;
      Xt[kc][m] = (mm < M && cc < Cin) ? Xb[(long)cc * M + mm] : 0.f;
    }
    __syncthreads();
#pragma unroll
    for (int kc = 0; kc < 16; ++kc) {
      float4 a = *(const float4*)&Wt[kc][ty * 4];
      float4 xv = *(const float4*)&Xt[kc][tx * 4];
      float av[4] = {a.x, a.y, a.z, a.w};
      float xr[4] = {xv.x, xv.y, xv.z, xv.w};
#pragma unroll
      for (int i = 0; i < 4; ++i)
#pragma unroll
        for (int j = 0; j < 4; ++j) acc[i][j] += av[i] * xr[j];
    }
    __syncthreads();
  }
#pragma unroll
  for (int i = 0; i < 4; ++i) {
    int oo = o0 + ty * 4 + i;
    if (oo >= Co) continue;
    float bv = bias ? bias[b * Co + oo] : 0.f;
#pragma unroll
    for (int j = 0; j < 4; ++j) {
      int mm = m0 + tx * 4 + j;
      if (mm < M) Y[((long)b * Co + oo) * M + mm] = acc[i][j] + bv;
    }
  }
}

// ---------------- wmod[o][c] = W[o][Ch+c] - W[o][c] ----------------
__global__ void wdiff_kernel(const float* __restrict__ W, int Wld, int Ch, int Co,
                             float* __restrict__ wmod) {
  int e = blockIdx.x * 256 + threadIdx.x;
  if (e < Co * Ch) {
    int o = e / Ch, c = e % Ch;
    wmod[e] = W[o * Wld + Ch + c] - W[o * Wld + c];
  }
}

// ---------------- z[b][o][n][k] = yn[b][o][idx[b][n][k]] + yc[b][o][n] ----------------
__global__ void __launch_bounds__(256, 4)
gather_kernel(const float* __restrict__ yn, const float* __restrict__ yc,
              const int* __restrict__ idx, float* __restrict__ z) {
  long e = (long)blockIdx.x * 256 + threadIdx.x;
  const long total = (long)B * 64 * N * K;
  if (e >= total) return;
  int k = (int)(e % K);
  long t1 = e / K;
  int n = (int)(t1 % N);
  long t2 = t1 / N;
  int o = (int)(t2 % 64);
  int b = (int)(t2 / 64);
  int j = idx[((long)b * N + n) * K + k];
  z[e] = yn[((long)b * 64 + o) * N + j] + yc[((long)b * 64 + o) * N + n];
}

// ---------------- per-channel partial sums (deterministic) ----------------
__global__ void __launch_bounds__(256, 4)
stats_kernel(const float* __restrict__ X, int C, int M,
             float* __restrict__ psum, float* __restrict__ psq) {
  int c = blockIdx.x, s = blockIdx.y;
  float sum = 0.f, sq = 0.f;
  for (int b = 0; b < B; ++b) {
    const float* p = X + ((long)b * C + c) * M;
    for (int m = s * 256 + threadIdx.x; m < M; m += SB * 256) {
      float v = p[m];
      sum += v; sq += v * v;
    }
  }
#pragma unroll
  for (int off = 32; off; off >>= 1) {
    sum += __shfl_down(sum, off);
    sq += __shfl_down(sq, off);
  }
  __shared__ float ls[8];
  int wid = threadIdx.x >> 6;
  if ((threadIdx.x & 63) == 0) { ls[wid] = sum; ls[4 + wid] = sq; }
  __syncthreads();
  if (threadIdx.x == 0) {
    psum[c * SB + s] = ls[0] + ls[1] + ls[2] + ls[3];
    psq[c * SB + s] = ls[4] + ls[5] + ls[6] + ls[7];
  }
}

__global__ void finalize_kernel(const float* __restrict__ psum, const float* __restrict__ psq,
                                const float* __restrict__ g, const float* __restrict__ bb,
                                float* __restrict__ scale, float* __restrict__ shift,
                                int C, float inv_n) {
  int c = blockIdx.x * 256 + threadIdx.x;
  if (c >= C) return;
  float s = 0.f, q = 0.f;
  for (int i = 0; i < SB; ++i) { s += psum[c * SB + i]; q += psq[c * SB + i]; }
  float mean = s * inv_n;
  float var = q * inv_n - mean * mean;
  float sc = g[c] * rsqrtf(var + BN_EPS);
  scale[c] = sc;
  shift[c] = bb[c] - mean * sc;
}

__global__ void __launch_bounds__(256, 4)
norm_kernel(float* __restrict__ X, const float* __restrict__ scale,
            const float* __restrict__ shift, int C, int M) {
  long e = (long)blockIdx.x * 256 + threadIdx.x;
  long total = (long)B * C * M;
  if (e >= total) return;
  int c = (int)((e / M) % C);
  float v = X[e] * scale[c] + shift[c];
  X[e] = v >= 0.f ? v : NEG * v;
}

// ---------------- max over K -> xc slice ----------------
__global__ void __launch_bounds__(256, 4)
maxk_kernel(const float* __restrict__ Z, float* __restrict__ xc, int coff) {
  long e = (long)blockIdx.x * 256 + threadIdx.x;
  if (e >= (long)B * 64 * N) return;
  int n = (int)(e % N);
  long t = e / N;
  int o = (int)(t % 64);
  int b = (int)(t / 64);
  const float* p = Z + (((long)(b * 64 + o) * N) + n) * K;
  float m = p[0];
#pragma unroll
  for (int k = 1; k < K; ++k) m = fmaxf(m, p[k]);
  xc[((long)b * 192 + coff + o) * N + n] = m;
}

// ---------------- max over N (z5 -> glob[0:1024]) ----------------
__global__ void __launch_bounds__(256, 4)
gmax_kernel(const float* __restrict__ Z5, float* __restrict__ glob) {
  int r = blockIdx.x;  // B*1024
  int b = r >> 10, o = r & 1023;
  const float* p = Z5 + (long)r * N;
  float m = -3.4e38f;
  for (int n = threadIdx.x; n < N; n += 256) m = fmaxf(m, p[n]);
#pragma unroll
  for (int off = 32; off; off >>= 1) m = fmaxf(m, __shfl_down(m, off));
  __shared__ float ls[4];
  int wid = threadIdx.x >> 6;
  if ((threadIdx.x & 63) == 0) ls[wid] = m;
  __syncthreads();
  if (threadIdx.x == 0)
    glob[b * 1088 + o] = fmaxf(fmaxf(ls[0], ls[1]), fmaxf(ls[2], ls[3]));
}

// ---------------- label branch (tiny) ----------------
__global__ void lfeat_kernel(const float* __restrict__ label, const float* __restrict__ W6,
                             const float* __restrict__ g6, const float* __restrict__ b6,
                             float* __restrict__ glob) {
  int o = threadIdx.x;
  if (o >= 64) return;
  float v[B];
  for (int b = 0; b < B; ++b) {
    float s = 0.f;
    for (int c = 0; c < 16; ++c) s += W6[o * 16 + c] * label[b * 16 + c];
    v[b] = s;
  }
  float mean = 0.f;
  for (int b = 0; b < B; ++b) mean += v[b];
  mean *= (1.f / B);
  float var = 0.f;
  for (int b = 0; b < B; ++b) var += (v[b] - mean) * (v[b] - mean);
  var *= (1.f / B);
  float sc = g6[o] * rsqrtf(var + BN_EPS);
  for (int b = 0; b < B; ++b) {
    float t = (v[b] - mean) * sc + b6[o];
    glob[b * 1088 + 1024 + o] = t >= 0.f ? t : NEG * t;
  }
}

// ---------------- bias0[b][o] = sum_c P0[o][192+c] * glob[b][c] ----------------
__global__ void __launch_bounds__(256, 4)
bias0_kernel(const float* __restrict__ P0, const float* __restrict__ glob,
             float* __restrict__ bias0) {
  int t = blockIdx.x * 256 + threadIdx.x;
  if (t >= B * 256) return;
  int b = t >> 8, o = t & 255;
  float s = 0.f;
  for (int c = 0; c < 1088; ++c) s += P0[o * 1280 + 192 + c] * glob[b * 1088 + c];
  bias0[b * 256 + o] = s;
}

extern "C" void kernel_launch(void* const* d_in, const int* in_sizes, int n_in,
                              void* d_out, int out_size, void* d_ws, size_t ws_size,
                              hipStream_t stream) {
  const float* pts = (const float*)d_in[0];
  const float* label = (const float*)d_in[1];
  const float* Wt7[7]; const float* gt[7]; const float* bt[7];
  for (int i = 0; i < 7; ++i) {
    Wt7[i] = (const float*)d_in[2 + 3 * i];
    gt[i] = (const float*)d_in[3 + 3 * i];
    bt[i] = (const float*)d_in[4 + 3 * i];
  }
  const float* P0 = (const float*)d_in[23];
  const float* P1 = (const float*)d_in[24];
  const float* P2 = (const float*)d_in[25];
  const float* P3 = (const float*)d_in[26];
  const float* pg0 = (const float*)d_in[27]; const float* pb0 = (const float*)d_in[28];
  const float* pg1 = (const float*)d_in[29]; const float* pb1 = (const float*)d_in[30];
  const float* pg2 = (const float*)d_in[31]; const float* pb2 = (const float*)d_in[32];
  float* out = (float*)d_out;

  float* w = (float*)d_ws;
  float* xx = w;                       // 20000
  int* idx = (int*)(w + 20000);        // 200000 ints
  float* yn = w + 220000;              // 1,280,000
  float* yc = yn + 1280000;            // 1,280,000
  float* wmod = yc + 1280000;          // 4096
  float* zA = wmod + 4096;             // 12,800,000
  float* zB = zA + 12800000;           // 12,800,000
  float* xc = zB + 12800000;           // 3,840,000
  float* z5 = xc + 3840000;            // 20,480,000
  float* glob = z5 + 20480000;         // 2176
  float* bias0 = glob + 2176;          // 512
  float* psum = bias0 + 512;           // 65536
  float* psq = psum + 65536;           // 65536
  float* scale = psq + 65536;          // 1024
  float* shift = scale + 1024;         // 1024
  float* hA = zA;                      // alias (B*256*N fits)
  float* hB = zB;
  // knn partial scratch aliases zA (free at knn time)
  float* pd = zA;                              // B*N*JS*K = 1.6e6
  int* pi = (int*)(zA + B * N * JS * K);       // 1.6e6 ints

  const long xcbs = (long)192 * N;
  const int qblocks = (N + 255) / 256;
  const int qtiles = (N + 63) / 64;

  auto gemm = [&](const float* W, int Wld, const float* X, long xbs, float* Y,
                  const float* bias, int Co, int Cin, int M) {
    dim3 g((M + 63) / 64, (Co + 63) / 64, B);
    gemm_kernel<<<g, 256, 0, stream>>>(W, Wld, X, xbs, Y, bias, Co, Cin, M);
  };
  auto bn_lrelu = [&](float* Z, int C, int M, const float* g, const float* bb) {
    stats_kernel<<<dim3(C, SB), 256, 0, stream>>>(Z, C, M, psum, psq);
    finalize_kernel<<<(C + 255) / 256, 256, 0, stream>>>(psum, psq, g, bb, scale, shift,
                                                         C, 1.f / (float)(B * M));
    long total = (long)B * C * M;
    norm_kernel<<<(int)((total + 255) / 256), 256, 0, stream>>>(Z, scale, shift, C, M);
  };
  auto knn3 = [&](const float* X, long bstride) {
    xx_kernel<<<dim3(qblocks, B), 256, 0, stream>>>(X, bstride, 3, xx);
    knn_partial_kernel<3, 256, 4><<<dim3(qblocks, JS, B), 256, 0, stream>>>(X, bstride, xx, pd, pi);
    knn_merge_kernel<<<(B * N + 255) / 256, 256, 0, stream>>>(pd, pi, idx);
  };
  auto knn64 = [&](const float* X, long bstride) {
    xx_kernel<<<dim3(qblocks, B), 256, 0, stream>>>(X, bstride, 64, xx);
    knn64_tiled_kernel<<<dim3(qtiles, JS, B), 256, 0, stream>>>(X, bstride, xx, pd, pi);
    knn_merge_kernel<<<(B * N + 255) / 256, 256, 0, stream>>>(pd, pi, idx);
  };
  auto edge_pre = [&](const float* Wconv, int Wld, int Cin, const float* X, long xbs) {
    gemm(Wconv, Wld, X, xbs, yn, nullptr, 64, Cin, N);
    wdiff_kernel<<<(64 * Cin + 255) / 256, 256, 0, stream>>>(Wconv, Wld, Cin, 64, wmod);
    gemm(wmod, Cin, X, xbs, yc, nullptr, 64, Cin, N);
    long tot = (long)B * 64 * N * K;
    gather_kernel<<<(int)((tot + 255) / 256), 256, 0, stream>>>(yn, yc, idx, zA);
  };

  // ---- Stage 1 ----
  knn3(pts, (long)3 * N);
  edge_pre(Wt7[0], 6, 3, pts, (long)3 * N);
  bn_lrelu(zA, 64, NK, gt[0], bt[0]);
  gemm(Wt7[1], 64, zA, (long)64 * NK, zB, nullptr, 64, 64, NK);
  bn_lrelu(zB, 64, NK, gt[1], bt[1]);
  maxk_kernel<<<(int)(((long)B * 64 * N + 255) / 256), 256, 0, stream>>>(zB, xc, 0);

  // ---- Stage 2 ----
  const float* x1 = xc;
  knn64(x1, xcbs);
  edge_pre(Wt7[2], 128, 64, x1, xcbs);
  bn_lrelu(zA, 64, NK, gt[2], bt[2]);
  gemm(Wt7[3], 64, zA, (long)64 * NK, zB, nullptr, 64, 64, NK);
  bn_lrelu(zB, 64, NK, gt[3], bt[3]);
  maxk_kernel<<<(int)(((long)B * 64 * N + 255) / 256), 256, 0, stream>>>(zB, xc, 64);

  // ---- Stage 3 ----
  const float* x2 = xc + (long)64 * N;
  knn64(x2, xcbs);
  edge_pre(Wt7[4], 128, 64, x2, xcbs);
  bn_lrelu(zA, 64, NK, gt[4], bt[4]);
  maxk_kernel<<<(int)(((long)B * 64 * N + 255) / 256), 256, 0, stream>>>(zA, xc, 128);

  // ---- Stage 4: global feature ----
  gemm(Wt7[5], 192, xc, xcbs, z5, nullptr, 1024, 192, N);
  bn_lrelu(z5, 1024, N, gt[5], bt[5]);
  gmax_kernel<<<B * 1024, 256, 0, stream>>>(z5, glob);
  lfeat_kernel<<<1, 64, 0, stream>>>(label, Wt7[6], gt[6], bt[6], glob);
  bias0_kernel<<<2, 256, 0, stream>>>(P0, glob, bias0);

  // ---- Stage 5: point head ----
  gemm(P0, 1280, xc, xcbs, hA, bias0, 256, 192, N);
  bn_lrelu(hA, 256, N, pg0, pb0);
  gemm(P1, 256, hA, (long)256 * N, hB, nullptr, 256, 256, N);
  bn_lrelu(hB, 256, N, pg1, pb1);
  gemm(P2, 256, hB, (long)256 * N, hA, nullptr, 128, 256, N);
  bn_lrelu(hA, 128, N, pg2, pb2);
  gemm(P3, 128, hA, (long)128 * N, out, nullptr, 6, 128, N);
}

// Round 4
// 3216.087 us; speedup vs baseline: 2.0192x; 2.0192x over previous
//
#include <hip/hip_runtime.h>
#include <math.h>

constexpr int B = 2;
constexpr int N = 10000;
constexpr int K = 10;
constexpr int NK = N * K;
constexpr float NEG = 0.2f;
constexpr float BN_EPS = 1e-5f;
constexpr int SB = 64;   // stats partial blocks per channel
constexpr int JS = 8;    // knn j-range splits
constexpr int JT = 64;   // knn64 j-tile

#define DEV __device__ __forceinline__

// ---------------- squared norms ----------------
__global__ void __launch_bounds__(256, 4)
xx_kernel(const float* __restrict__ x, long bstride, int C,
          float* __restrict__ xx) {
  int n = blockIdx.x * 256 + threadIdx.x;
  int b = blockIdx.y;
  if (n >= N) return;
  const float* xb = x + (long)b * bstride;
  float s = 0.f;
  for (int c = 0; c < C; ++c) { float v = xb[(long)c * N + n]; s += v * v; }
  xx[b * N + n] = s;
}

// ---------------- u64 packed key: (monotone f32 bits)<<32 | j ----------------
// Total order == lexicographic (d, j) ascending == lax.top_k stable tie-break.
DEV unsigned long long pack_key(float d, unsigned int j) {
  unsigned int bits = __float_as_uint(d);
  bits ^= ((unsigned int)((int)bits >> 31)) | 0x80000000u;
  return ((unsigned long long)bits << 32) | j;
}
DEV void topk_u64(unsigned long long (&best)[K], unsigned long long key) {
#pragma unroll
  for (int s = 0; s < K; ++s) {
    unsigned long long b = best[s];
    bool lt = key < b;
    best[s] = lt ? key : b;
    key = lt ? b : key;
  }
}
constexpr unsigned long long KEY_MAX = 0xFFFFFFFFFFFFFFFFull;

// ---------------- knn partial for C=3 (cheap, per-thread query) ----------------
template<int C, int TJ, int PAD>
__global__ void __launch_bounds__(256, 4)
knn_partial_kernel(const float* __restrict__ x, long bstride,
                   const float* __restrict__ xx,
                   unsigned long long* __restrict__ pk) {
  __shared__ __align__(16) float sx[TJ][PAD];
  __shared__ float sxx[TJ];
  int b = blockIdx.z;
  int js = blockIdx.y;
  int q = blockIdx.x * 256 + threadIdx.x;
  bool valid = q < N;
  const int CH = (N + JS - 1) / JS;
  int jbeg = js * CH;
  int jend = min(N, jbeg + CH);
  const float* xb = x + (long)b * bstride;
  float xi[C];
  float xxi = 0.f;
  if (valid) {
#pragma unroll
    for (int c = 0; c < C; ++c) xi[c] = xb[(long)c * N + q];
    xxi = xx[b * N + q];
  }
  unsigned long long best[K];
#pragma unroll
  for (int k = 0; k < K; ++k) best[k] = KEY_MAX;

  for (int j0 = jbeg; j0 < jend; j0 += TJ) {
    int cnt = min(TJ, jend - j0);
    __syncthreads();
    for (int e = threadIdx.x; e < C * TJ; e += 256) {
      int tj = e & (TJ - 1);
      int c = e / TJ;
      sx[tj][c] = (tj < cnt) ? xb[(long)c * N + j0 + tj] : 0.f;
    }
    for (int e = threadIdx.x; e < TJ; e += 256)
      sxx[e] = (e < cnt) ? xx[b * N + j0 + e] : 0.f;
    __syncthreads();
    if (!valid) continue;
    for (int tj = 0; tj < cnt; ++tj) {
      float dot = 0.f;
#pragma unroll
      for (int c = 0; c < C; ++c) dot += xi[c] * sx[tj][c];
      float d = xxi - 2.f * dot + sxx[tj];
      int j = j0 + tj;
      if (j != q) {
        unsigned long long key = pack_key(d, (unsigned int)j);
        if (key < best[K - 1]) topk_u64(best, key);
      }
    }
  }
  if (valid) {
    long base = ((long)(b * N + q) * JS + js) * K;
#pragma unroll
    for (int k = 0; k < K; ++k) pk[base + k] = best[k];
  }
}

// ---------------- knn C=64: tiled distance-GEMM + fused top-k ----------------
// Block = 64 queries x (N/JS) j-range, J-tiles of 64.
// Thread (tx,ty): q = tx*4+i, j = ty*4+jj -> acc[4][4].
// Distances stored transposed D[j][q] (lane-stride-1 scan, conflict-free).
// Self-exclusion + OOB handled by INF sentinels. u64-key top-K in registers.
__global__ void __launch_bounds__(256, 4)
knn64_tiled_kernel(const float* __restrict__ x, long bstride,
                   const float* __restrict__ xx,
                   unsigned long long* __restrict__ pk) {
  __shared__ __align__(16) float smem[64 * 68 * 2 + 128];
  float* Qt = smem;                 // [c][q] pad 68
  float* JD = smem + 64 * 68;      // [c][j] pad 68; reused as D[j][q] pad 68
  float* xxq = smem + 64 * 68 * 2;
  float* xxj = xxq + 64;
  int b = blockIdx.z, js = blockIdx.y, qt = blockIdx.x;
  int t = threadIdx.x;
  const float* xb = x + (long)b * bstride;
  const float* xxb = xx + b * N;
  int q0 = qt * 64;
#pragma unroll
  for (int r = 0; r < 16; ++r) {
    int e = t + r * 256;
    int q = e & 63, c = e >> 6;
    int qg = q0 + q;
    Qt[c * 68 + q] = (qg < N) ? xb[(long)c * N + qg] : 0.f;
  }
  if (t < 64) xxq[t] = (q0 + t < N) ? xxb[q0 + t] : 0.f;

  const int CH = N / JS;               // 1250
  int jbeg = js * CH, jend = jbeg + CH;
  int tx = t & 15, ty = t >> 4;        // compute coords: q-group tx, j-group ty
  int sq = t & 63, quarter = t >> 6;   // scan coords (quarter == wave id)

  unsigned long long best[K];
#pragma unroll
  for (int k = 0; k < K; ++k) best[k] = KEY_MAX;

  for (int jb = jbeg; jb < jend; jb += JT) {
    __syncthreads();  // previous scan done before overwriting JD
    // load J tile (64 j x 64 c), [c][j]
#pragma unroll
    for (int r = 0; r < 16; ++r) {
      int e = t + r * 256;
      int j = e & 63, c = e >> 6;
      int jg = jb + j;
      JD[c * 68 + j] = (jg < jend) ? xb[(long)c * N + jg] : 0.f;
    }
    if (t < 64) xxj[t] = (jb + t < jend) ? xxb[jb + t] : 3.4e38f;
    __syncthreads();

    float acc[4][4] = {};
#pragma unroll 4
    for (int c = 0; c < 64; ++c) {
      float4 aq = *(const float4*)&Qt[c * 68 + tx * 4];   // 4 queries
      float4 bj = *(const float4*)&JD[c * 68 + ty * 4];   // 4 j (broadcast)
      float av[4] = {aq.x, aq.y, aq.z, aq.w};
      float bv[4] = {bj.x, bj.y, bj.z, bj.w};
#pragma unroll
      for (int i = 0; i < 4; ++i)
#pragma unroll
        for (int jj = 0; jj < 4; ++jj) acc[i][jj] += av[i] * bv[jj];
    }
    __syncthreads();  // all reads of JD done before D overwrite

    // distances (with self-exclusion) -> D[j][q]
    float4 xxjv = *(const float4*)&xxj[ty * 4];
    float xjv[4] = {xxjv.x, xxjv.y, xxjv.z, xxjv.w};
    int selbase = q0 + tx * 4 - jb - ty * 4;   // (q - j) offset
    float d4[4][4];
#pragma unroll
    for (int i = 0; i < 4; ++i) {
      float xq = xxq[tx * 4 + i];
#pragma unroll
      for (int jj = 0; jj < 4; ++jj) {
        float dv = xq - 2.f * acc[i][jj] + xjv[jj];
        d4[i][jj] = (selbase + i == jj) ? 3.4e38f : dv;
      }
    }
#pragma unroll
    for (int jj = 0; jj < 4; ++jj) {
      float4 sv = make_float4(d4[0][jj], d4[1][jj], d4[2][jj], d4[3][jj]);
      *(float4*)&JD[(ty * 4 + jj) * 68 + tx * 4] = sv;
    }
    __syncthreads();

    // scan: thread owns query sq, j sub-range [quarter*16, quarter*16+16)
    // D[jl][sq]: lane-stride-1, conflict-free, immediate offsets.
#pragma unroll 4
    for (int jj = 0; jj < 16; ++jj) {
      int jl = quarter * 16 + jj;
      float dv = JD[jl * 68 + sq];
      unsigned long long key = pack_key(dv, (unsigned int)(jb + jl));
      if (key < best[K - 1]) topk_u64(best, key);
    }
  }
  __syncthreads();
  // in-block merge across the 4 quarters
  unsigned long long* mb = (unsigned long long*)smem;
#pragma unroll
  for (int k = 0; k < K; ++k) mb[(sq * 4 + quarter) * K + k] = best[k];
  __syncthreads();
  if (t < 64 && q0 + t < N) {
    unsigned long long fb[K];
#pragma unroll
    for (int k = 0; k < K; ++k) fb[k] = KEY_MAX;
    for (int s = 0; s < 4; ++s)
#pragma unroll
      for (int k = 0; k < K; ++k) {
        unsigned long long key = mb[(t * 4 + s) * K + k];
        if (key < fb[K - 1]) topk_u64(fb, key);
      }
    long base = ((long)(b * N + q0 + t) * JS + js) * K;
#pragma unroll
    for (int k = 0; k < K; ++k) pk[base + k] = fb[k];
  }
}

// ---------------- knn merge (JS sorted partial lists -> final top-K) ----------------
__global__ void __launch_bounds__(256, 4)
knn_merge_kernel(const unsigned long long* __restrict__ pk, int* __restrict__ idx) {
  int t = blockIdx.x * 256 + threadIdx.x;
  if (t >= B * N) return;
  unsigned long long best[K];
#pragma unroll
  for (int k = 0; k < K; ++k) best[k] = KEY_MAX;
  for (int s = 0; s < JS; ++s) {
    long base = ((long)t * JS + s) * K;
#pragma unroll
    for (int k = 0; k < K; ++k) {
      unsigned long long key = pk[base + k];
      if (key < best[K - 1]) topk_u64(best, key);
    }
  }
#pragma unroll
  for (int k = 0; k < K; ++k)
    idx[(long)t * K + k] = (int)(best[k] & 0xFFFFFFFFull);
}

// ---------------- generic tiled SGEMM: Y[b][o][m] = sum_c W[o*Wld+c] * X[b][c][m] (+bias[b][o]) ----
__global__ void __launch_bounds__(256, 4)
gemm_kernel(const float* __restrict__ W, int Wld,
            const float* __restrict__ X, long xbstride,
            float* __restrict__ Y, const float* __restrict__ bias,
            int Co, int Cin, int M) {
  __shared__ float Wt[16][64];
  __shared__ float Xt[16][64];
  int b = blockIdx.z;
  int m0 = blockIdx.x * 64;
  int o0 = blockIdx.y * 64;
  const float* Xb = X + (long)b * xbstride;
  int t = threadIdx.x;
  int tx = t & 15, ty = t >> 4;
  float acc[4][4] = {};
  for (int c0 = 0; c0 < Cin; c0 += 16) {
#pragma unroll
    for (int r = 0; r < 4; ++r) {
      int e = t + r * 256;
      int o = e & 63, kc = e >> 6;
      int oo = o0 + o, cc = c0 + kc;
      Wt[kc][o] = (oo < Co && cc < Cin) ? W[(long)oo * Wld + cc] : 0.f;
    }
#pragma unroll
    for (int r = 0; r < 4; ++r) {
      int e = t + r * 256;
      int m = e & 63, kc = e >> 6;
      int mm = m0 + m, cc = c0 + kc;
      Xt[kc][m] = (mm < M && cc < Cin) ? Xb[(long)cc * M + mm] : 0.f;
    }
    __syncthreads();
#pragma unroll
    for (int kc = 0; kc < 16; ++kc) {
      float4 a = *(const float4*)&Wt[kc][ty * 4];
      float4 xv = *(const float4*)&Xt[kc][tx * 4];
      float av[4] = {a.x, a.y, a.z, a.w};
      float xr[4] = {xv.x, xv.y, xv.z, xv.w};
#pragma unroll
      for (int i = 0; i < 4; ++i)
#pragma unroll
        for (int j = 0; j < 4; ++j) acc[i][j] += av[i] * xr[j];
    }
    __syncthreads();
  }
#pragma unroll
  for (int i = 0; i < 4; ++i) {
    int oo = o0 + ty * 4 + i;
    if (oo >= Co) continue;
    float bv = bias ? bias[b * Co + oo] : 0.f;
#pragma unroll
    for (int j = 0; j < 4; ++j) {
      int mm = m0 + tx * 4 + j;
      if (mm < M) Y[((long)b * Co + oo) * M + mm] = acc[i][j] + bv;
    }
  }
}

// ---------------- wmod[o][c] = W[o][Ch+c] - W[o][c] ----------------
__global__ void wdiff_kernel(const float* __restrict__ W, int Wld, int Ch, int Co,
                             float* __restrict__ wmod) {
  int e = blockIdx.x * 256 + threadIdx.x;
  if (e < Co * Ch) {
    int o = e / Ch, c = e % Ch;
    wmod[e] = W[o * Wld + Ch + c] - W[o * Wld + c];
  }
}

// ---------------- z[b][o][n][k] = yn[b][o][idx[b][n][k]] + yc[b][o][n] ----------------
__global__ void __launch_bounds__(256, 4)
gather_kernel(const float* __restrict__ yn, const float* __restrict__ yc,
              const int* __restrict__ idx, float* __restrict__ z) {
  long e = (long)blockIdx.x * 256 + threadIdx.x;
  const long total = (long)B * 64 * N * K;
  if (e >= total) return;
  int k = (int)(e % K);
  long t1 = e / K;
  int n = (int)(t1 % N);
  long t2 = t1 / N;
  int o = (int)(t2 % 64);
  int b = (int)(t2 / 64);
  int j = idx[((long)b * N + n) * K + k];
  z[e] = yn[((long)b * 64 + o) * N + j] + yc[((long)b * 64 + o) * N + n];
}

// ---------------- per-channel partial sums (deterministic) ----------------
__global__ void __launch_bounds__(256, 4)
stats_kernel(const float* __restrict__ X, int C, int M,
             float* __restrict__ psum, float* __restrict__ psq) {
  int c = blockIdx.x, s = blockIdx.y;
  float sum = 0.f, sq = 0.f;
  for (int b = 0; b < B; ++b) {
    const float* p = X + ((long)b * C + c) * M;
    for (int m = s * 256 + threadIdx.x; m < M; m += SB * 256) {
      float v = p[m];
      sum += v; sq += v * v;
    }
  }
#pragma unroll
  for (int off = 32; off; off >>= 1) {
    sum += __shfl_down(sum, off);
    sq += __shfl_down(sq, off);
  }
  __shared__ float ls[8];
  int wid = threadIdx.x >> 6;
  if ((threadIdx.x & 63) == 0) { ls[wid] = sum; ls[4 + wid] = sq; }
  __syncthreads();
  if (threadIdx.x == 0) {
    psum[c * SB + s] = ls[0] + ls[1] + ls[2] + ls[3];
    psq[c * SB + s] = ls[4] + ls[5] + ls[6] + ls[7];
  }
}

__global__ void finalize_kernel(const float* __restrict__ psum, const float* __restrict__ psq,
                                const float* __restrict__ g, const float* __restrict__ bb,
                                float* __restrict__ scale, float* __restrict__ shift,
                                int C, float inv_n) {
  int c = blockIdx.x * 256 + threadIdx.x;
  if (c >= C) return;
  float s = 0.f, q = 0.f;
  for (int i = 0; i < SB; ++i) { s += psum[c * SB + i]; q += psq[c * SB + i]; }
  float mean = s * inv_n;
  float var = q * inv_n - mean * mean;
  float sc = g[c] * rsqrtf(var + BN_EPS);
  scale[c] = sc;
  shift[c] = bb[c] - mean * sc;
}

__global__ void __launch_bounds__(256, 4)
norm_kernel(float* __restrict__ X, const float* __restrict__ scale,
            const float* __restrict__ shift, int C, int M) {
  long e = (long)blockIdx.x * 256 + threadIdx.x;
  long total = (long)B * C * M;
  if (e >= total) return;
  int c = (int)((e / M) % C);
  float v = X[e] * scale[c] + shift[c];
  X[e] = v >= 0.f ? v : NEG * v;
}

// ---------------- max over K -> xc slice ----------------
__global__ void __launch_bounds__(256, 4)
maxk_kernel(const float* __restrict__ Z, float* __restrict__ xc, int coff) {
  long e = (long)blockIdx.x * 256 + threadIdx.x;
  if (e >= (long)B * 64 * N) return;
  int n = (int)(e % N);
  long t = e / N;
  int o = (int)(t % 64);
  int b = (int)(t / 64);
  const float* p = Z + (((long)(b * 64 + o) * N) + n) * K;
  float m = p[0];
#pragma unroll
  for (int k = 1; k < K; ++k) m = fmaxf(m, p[k]);
  xc[((long)b * 192 + coff + o) * N + n] = m;
}

// ---------------- max over N (z5 -> glob[0:1024]) ----------------
__global__ void __launch_bounds__(256, 4)
gmax_kernel(const float* __restrict__ Z5, float* __restrict__ glob) {
  int r = blockIdx.x;  // B*1024
  int b = r >> 10, o = r & 1023;
  const float* p = Z5 + (long)r * N;
  float m = -3.4e38f;
  for (int n = threadIdx.x; n < N; n += 256) m = fmaxf(m, p[n]);
#pragma unroll
  for (int off = 32; off; off >>= 1) m = fmaxf(m, __shfl_down(m, off));
  __shared__ float ls[4];
  int wid = threadIdx.x >> 6;
  if ((threadIdx.x & 63) == 0) ls[wid] = m;
  __syncthreads();
  if (threadIdx.x == 0)
    glob[b * 1088 + o] = fmaxf(fmaxf(ls[0], ls[1]), fmaxf(ls[2], ls[3]));
}

// ---------------- label branch (tiny) ----------------
__global__ void lfeat_kernel(const float* __restrict__ label, const float* __restrict__ W6,
                             const float* __restrict__ g6, const float* __restrict__ b6,
                             float* __restrict__ glob) {
  int o = threadIdx.x;
  if (o >= 64) return;
  float v[B];
  for (int b = 0; b < B; ++b) {
    float s = 0.f;
    for (int c = 0; c < 16; ++c) s += W6[o * 16 + c] * label[b * 16 + c];
    v[b] = s;
  }
  float mean = 0.f;
  for (int b = 0; b < B; ++b) mean += v[b];
  mean *= (1.f / B);
  float var = 0.f;
  for (int b = 0; b < B; ++b) var += (v[b] - mean) * (v[b] - mean);
  var *= (1.f / B);
  float sc = g6[o] * rsqrtf(var + BN_EPS);
  for (int b = 0; b < B; ++b) {
    float t = (v[b] - mean) * sc + b6[o];
    glob[b * 1088 + 1024 + o] = t >= 0.f ? t : NEG * t;
  }
}

// ---------------- bias0[b][o] = sum_c P0[o][192+c] * glob[b][c] ----------------
__global__ void __launch_bounds__(256, 4)
bias0_kernel(const float* __restrict__ P0, const float* __restrict__ glob,
             float* __restrict__ bias0) {
  int t = blockIdx.x * 256 + threadIdx.x;
  if (t >= B * 256) return;
  int b = t >> 8, o = t & 255;
  float s = 0.f;
  for (int c = 0; c < 1088; ++c) s += P0[o * 1280 + 192 + c] * glob[b * 1088 + c];
  bias0[b * 256 + o] = s;
}

extern "C" void kernel_launch(void* const* d_in, const int* in_sizes, int n_in,
                              void* d_out, int out_size, void* d_ws, size_t ws_size,
                              hipStream_t stream) {
  const float* pts = (const float*)d_in[0];
  const float* label = (const float*)d_in[1];
  const float* Wt7[7]; const float* gt[7]; const float* bt[7];
  for (int i = 0; i < 7; ++i) {
    Wt7[i] = (const float*)d_in[2 + 3 * i];
    gt[i] = (const float*)d_in[3 + 3 * i];
    bt[i] = (const float*)d_in[4 + 3 * i];
  }
  const float* P0 = (const float*)d_in[23];
  const float* P1 = (const float*)d_in[24];
  const float* P2 = (const float*)d_in[25];
  const float* P3 = (const float*)d_in[26];
  const float* pg0 = (const float*)d_in[27]; const float* pb0 = (const float*)d_in[28];
  const float* pg1 = (const float*)d_in[29]; const float* pb1 = (const float*)d_in[30];
  const float* pg2 = (const float*)d_in[31]; const float* pb2 = (const float*)d_in[32];
  float* out = (float*)d_out;

  float* w = (float*)d_ws;
  float* xx = w;                       // 20000
  int* idx = (int*)(w + 20000);        // 200000 ints
  float* yn = w + 220000;              // 1,280,000
  float* yc = yn + 1280000;            // 1,280,000
  float* wmod = yc + 1280000;          // 4096
  float* zA = wmod + 4096;             // 12,800,000
  float* zB = zA + 12800000;           // 12,800,000
  float* xc = zB + 12800000;           // 3,840,000
  float* z5 = xc + 3840000;            // 20,480,000
  float* glob = z5 + 20480000;         // 2176
  float* bias0 = glob + 2176;          // 512
  float* psum = bias0 + 512;           // 65536
  float* psq = psum + 65536;           // 65536
  float* scale = psq + 65536;          // 1024
  float* shift = scale + 1024;         // 1024
  float* hA = zA;                      // alias (B*256*N fits)
  float* hB = zB;
  // knn scratch aliases zA (free at knn time): B*N*JS*K u64 = 12.8 MB
  unsigned long long* pk = (unsigned long long*)zA;

  const long xcbs = (long)192 * N;
  const int qblocks = (N + 255) / 256;
  const int qtiles = (N + 63) / 64;

  auto gemm = [&](const float* W, int Wld, const float* X, long xbs, float* Y,
                  const float* bias, int Co, int Cin, int M) {
    dim3 g((M + 63) / 64, (Co + 63) / 64, B);
    gemm_kernel<<<g, 256, 0, stream>>>(W, Wld, X, xbs, Y, bias, Co, Cin, M);
  };
  auto bn_lrelu = [&](float* Z, int C, int M, const float* g, const float* bb) {
    stats_kernel<<<dim3(C, SB), 256, 0, stream>>>(Z, C, M, psum, psq);
    finalize_kernel<<<(C + 255) / 256, 256, 0, stream>>>(psum, psq, g, bb, scale, shift,
                                                         C, 1.f / (float)(B * M));
    long total = (long)B * C * M;
    norm_kernel<<<(int)((total + 255) / 256), 256, 0, stream>>>(Z, scale, shift, C, M);
  };
  auto knn3 = [&](const float* X, long bstride) {
    xx_kernel<<<dim3(qblocks, B), 256, 0, stream>>>(X, bstride, 3, xx);
    knn_partial_kernel<3, 256, 4><<<dim3(qblocks, JS, B), 256, 0, stream>>>(X, bstride, xx, pk);
    knn_merge_kernel<<<(B * N + 255) / 256, 256, 0, stream>>>(pk, idx);
  };
  auto knn64 = [&](const float* X, long bstride) {
    xx_kernel<<<dim3(qblocks, B), 256, 0, stream>>>(X, bstride, 64, xx);
    knn64_tiled_kernel<<<dim3(qtiles, JS, B), 256, 0, stream>>>(X, bstride, xx, pk);
    knn_merge_kernel<<<(B * N + 255) / 256, 256, 0, stream>>>(pk, idx);
  };
  auto edge_pre = [&](const float* Wconv, int Wld, int Cin, const float* X, long xbs) {
    gemm(Wconv, Wld, X, xbs, yn, nullptr, 64, Cin, N);
    wdiff_kernel<<<(64 * Cin + 255) / 256, 256, 0, stream>>>(Wconv, Wld, Cin, 64, wmod);
    gemm(wmod, Cin, X, xbs, yc, nullptr, 64, Cin, N);
    long tot = (long)B * 64 * N * K;
    gather_kernel<<<(int)((tot + 255) / 256), 256, 0, stream>>>(yn, yc, idx, zA);
  };

  // ---- Stage 1 ----
  knn3(pts, (long)3 * N);
  edge_pre(Wt7[0], 6, 3, pts, (long)3 * N);
  bn_lrelu(zA, 64, NK, gt[0], bt[0]);
  gemm(Wt7[1], 64, zA, (long)64 * NK, zB, nullptr, 64, 64, NK);
  bn_lrelu(zB, 64, NK, gt[1], bt[1]);
  maxk_kernel<<<(int)(((long)B * 64 * N + 255) / 256), 256, 0, stream>>>(zB, xc, 0);

  // ---- Stage 2 ----
  const float* x1 = xc;
  knn64(x1, xcbs);
  edge_pre(Wt7[2], 128, 64, x1, xcbs);
  bn_lrelu(zA, 64, NK, gt[2], bt[2]);
  gemm(Wt7[3], 64, zA, (long)64 * NK, zB, nullptr, 64, 64, NK);
  bn_lrelu(zB, 64, NK, gt[3], bt[3]);
  maxk_kernel<<<(int)(((long)B * 64 * N + 255) / 256), 256, 0, stream>>>(zB, xc, 64);

  // ---- Stage 3 ----
  const float* x2 = xc + (long)64 * N;
  knn64(x2, xcbs);
  edge_pre(Wt7[4], 128, 64, x2, xcbs);
  bn_lrelu(zA, 64, NK, gt[4], bt[4]);
  maxk_kernel<<<(int)(((long)B * 64 * N + 255) / 256), 256, 0, stream>>>(zA, xc, 128);

  // ---- Stage 4: global feature ----
  gemm(Wt7[5], 192, xc, xcbs, z5, nullptr, 1024, 192, N);
  bn_lrelu(z5, 1024, N, gt[5], bt[5]);
  gmax_kernel<<<B * 1024, 256, 0, stream>>>(z5, glob);
  lfeat_kernel<<<1, 64, 0, stream>>>(label, Wt7[6], gt[6], bt[6], glob);
  bias0_kernel<<<2, 256, 0, stream>>>(P0, glob, bias0);

  // ---- Stage 5: point head ----
  gemm(P0, 1280, xc, xcbs, hA, bias0, 256, 192, N);
  bn_lrelu(hA, 256, N, pg0, pb0);
  gemm(P1, 256, hA, (long)256 * N, hB, nullptr, 256, 256, N);
  bn_lrelu(hB, 256, N, pg1, pb1);
  gemm(P2, 256, hB, (long)256 * N, hA, nullptr, 128, 256, N);
  bn_lrelu(hA, 128, N, pg2, pb2);
  gemm(P3, 128, hA, (long)128 * N, out, nullptr, 6, 128, N);
}